// Round 1
// baseline (4958.937 us; speedup 1.0000x reference)
//
#include <hip/hip_runtime.h>
#include <math.h>

// ---------------------------------------------------------------------------
// SeqToSeq: enc LSTM (U=356, T=7, F=69) -> dec LSTM (F=45) -> MLP
// Round 0: correct fp32 baseline. Generic tiled GEMM with dual-A/dual-B
// (K-concat for [x_t | h] @ [W ; U]) and fused bias/relu/tanh epilogue.
// ---------------------------------------------------------------------------

#define BM 128
#define BN 128
#define BK 8
#define AS_STRIDE 132   // padded: 132*4 % 16 == 0 keeps b128 alignment

enum { EPI_BIAS = 0, EPI_RELU = 1, EPI_TANH = 2 };

// C[M,N] = act( [A1 | A2] @ [B1 ; B2] + bias )
// k < K1 reads A1[row*lda1 + k], B1[k*N + n]
// k >= K1 reads A2[row*lda2 + (k-K1)], B2[(k-K1)*N + n]
// M must be a multiple of BM (8192 here). N,K arbitrary (guarded).
template <int EPI>
__global__ __launch_bounds__(256)
void gemm_k(const float* __restrict__ A1, int lda1, int K1,
            const float* __restrict__ A2, int lda2,
            const float* __restrict__ B1, const float* __restrict__ B2,
            const float* __restrict__ bias,
            float* __restrict__ C, int ldc,
            int M, int N, int K)
{
    __shared__ float As[BK * AS_STRIDE];  // transposed: As[k][m]
    __shared__ float Bs[BK * BN];         // Bs[k][n]

    const int tid = threadIdx.x;
    const int tx = tid & 15;          // 0..15 -> col group (8 cols each)
    const int ty = tid >> 4;          // 0..15 -> row group (8 rows each)
    const int row0 = blockIdx.x * BM;
    const int col0 = blockIdx.y * BN;

    // A-tile loader: 128 rows x 8 k. thread t -> row t>>1, k-quad (t&1)*4
    const int a_r  = tid >> 1;
    const int a_kq = (tid & 1) * 4;
    // B-tile loader: 8 k x 128 n. thread t -> k row t>>5, col quad (t&31)*4
    const int b_kr = tid >> 5;
    const int b_c4 = (tid & 31) * 4;

    float acc[8][8];
    #pragma unroll
    for (int i = 0; i < 8; ++i)
        #pragma unroll
        for (int j = 0; j < 8; ++j) acc[i][j] = 0.f;

    for (int k0 = 0; k0 < K; k0 += BK) {
        // ---- stage A (transpose into As[k][m]) ----
        #pragma unroll
        for (int j = 0; j < 4; ++j) {
            const int k = k0 + a_kq + j;
            float v = 0.f;
            if (k < K) {
                const long grow = row0 + a_r;
                v = (k < K1) ? A1[grow * lda1 + k]
                             : A2[grow * lda2 + (k - K1)];
            }
            As[(a_kq + j) * AS_STRIDE + a_r] = v;
        }
        // ---- stage B ----
        {
            const int k = k0 + b_kr;
            #pragma unroll
            for (int j = 0; j < 4; ++j) {
                const int n = col0 + b_c4 + j;
                float v = 0.f;
                if (k < K && n < N)
                    v = (k < K1) ? B1[(long)k * N + n]
                                 : B2[(long)(k - K1) * N + n];
                Bs[b_kr * BN + b_c4 + j] = v;
            }
        }
        __syncthreads();

        #pragma unroll
        for (int kk = 0; kk < BK; ++kk) {
            float a[8], b[8];
            #pragma unroll
            for (int i = 0; i < 8; ++i) a[i] = As[kk * AS_STRIDE + ty * 8 + i];
            #pragma unroll
            for (int j = 0; j < 8; ++j) b[j] = Bs[kk * BN + tx * 8 + j];
            #pragma unroll
            for (int i = 0; i < 8; ++i)
                #pragma unroll
                for (int j = 0; j < 8; ++j)
                    acc[i][j] = fmaf(a[i], b[j], acc[i][j]);
        }
        __syncthreads();
    }

    // ---- epilogue ----
    #pragma unroll
    for (int i = 0; i < 8; ++i) {
        const long r = row0 + ty * 8 + i;
        #pragma unroll
        for (int j = 0; j < 8; ++j) {
            const int n = col0 + tx * 8 + j;
            if (n < N) {
                float v = acc[i][j] + bias[n];
                if (EPI == EPI_RELU) v = fmaxf(v, 0.f);
                if (EPI == EPI_TANH) v = tanhf(v);
                C[r * ldc + n] = v;
            }
        }
    }
}

// One thread per (b,u): gate nonlinearities + state update.
// z layout: [B, 4U] gate order i,f,g,o.  dec (optional): write h to
// dec[b*dec_ld + dec_off + u]  (decoded [B, T*U] flattened).
__global__ void lstm_gates_k(const float* __restrict__ z,
                             float* __restrict__ h, float* __restrict__ c,
                             float* __restrict__ dec, int dec_off, int dec_ld,
                             int BU, int Uc)
{
    const int idx = blockIdx.x * blockDim.x + threadIdx.x;
    if (idx >= BU) return;
    const int b = idx / Uc;
    const int u = idx - b * Uc;
    const float* zb = z + (long)b * 4 * Uc;
    const float zi = zb[u];
    const float zf = zb[u + Uc];
    const float zg = zb[u + 2 * Uc];
    const float zo = zb[u + 3 * Uc];
    const float ig = 1.f / (1.f + expf(-zi));
    const float fg = 1.f / (1.f + expf(-zf));
    const float og = 1.f / (1.f + expf(-zo));
    const float gv = tanhf(zg);
    const float cv = fg * c[idx] + ig * gv;
    c[idx] = cv;
    const float hv = og * tanhf(cv);
    h[idx] = hv;
    if (dec) dec[(long)b * dec_ld + dec_off + u] = hv;
}

extern "C" void kernel_launch(void* const* d_in, const int* in_sizes, int n_in,
                              void* d_out, int out_size, void* d_ws, size_t ws_size,
                              hipStream_t stream)
{
    const float* x     = (const float*)d_in[0];   // [8192,7,69]
    const float* m     = (const float*)d_in[1];   // [8192,7,45]
    const float* enc_W = (const float*)d_in[2];   // [69,1424]
    const float* enc_U = (const float*)d_in[3];   // [356,1424]
    const float* enc_b = (const float*)d_in[4];   // [1424]
    const float* dec_W = (const float*)d_in[5];   // [45,1424]
    const float* dec_Um= (const float*)d_in[6];   // [356,1424]
    const float* dec_b = (const float*)d_in[7];   // [1424]
    const float* W_map = (const float*)d_in[8];   // [2492,1024]
    const float* b_map = (const float*)d_in[9];
    const float* W1    = (const float*)d_in[10];
    const float* b1    = (const float*)d_in[11];
    const float* W2    = (const float*)d_in[12];
    const float* b2    = (const float*)d_in[13];
    const float* W3    = (const float*)d_in[14];
    const float* b3    = (const float*)d_in[15];
    const float* W_out = (const float*)d_in[16];  // [1024,168]
    const float* b_out = (const float*)d_in[17];
    float* out = (float*)d_out;                   // [8192,168]

    const int B = 8192, T = 7, U = 356, N4 = 4 * U;  // N4 = 1424
    const int FEnc = 69, FDec = 45;

    // workspace map (floats): ~219 MB total
    float* ws    = (float*)d_ws;
    float* h     = ws;                         // B*U
    float* c     = h    + (size_t)B * U;       // B*U
    float* z     = c    + (size_t)B * U;       // B*N4
    float* decd  = z    + (size_t)B * N4;      // B*T*U (2492 per row)
    float* buf1  = decd + (size_t)B * T * U;   // B*1024
    float* buf2  = buf1 + (size_t)B * 1024;    // B*1024

    hipMemsetAsync(h, 0, (size_t)B * U * sizeof(float), stream);
    hipMemsetAsync(c, 0, (size_t)B * U * sizeof(float), stream);

    const dim3 blk(256);
    auto grid = [](int M, int N) {
        return dim3((unsigned)((M + BM - 1) / BM), (unsigned)((N + BN - 1) / BN));
    };
    const int gates_grid = (B * U + 255) / 256;

    // ---- encoder: z = [x_t | h] @ [enc_W ; enc_U] + enc_b ----
    for (int t = 0; t < T; ++t) {
        gemm_k<EPI_BIAS><<<grid(B, N4), blk, 0, stream>>>(
            x + t * FEnc, T * FEnc, FEnc, h, U,
            enc_W, enc_U, enc_b, z, N4, B, N4, FEnc + U);
        lstm_gates_k<<<gates_grid, 256, 0, stream>>>(
            z, h, c, nullptr, 0, 0, B * U, U);
    }
    // ---- decoder (seeded with encoder h,c): store h into decoded ----
    for (int t = 0; t < T; ++t) {
        gemm_k<EPI_BIAS><<<grid(B, N4), blk, 0, stream>>>(
            m + t * FDec, T * FDec, FDec, h, U,
            dec_W, dec_Um, dec_b, z, N4, B, N4, FDec + U);
        lstm_gates_k<<<gates_grid, 256, 0, stream>>>(
            z, h, c, decd, t * U, T * U, B * U, U);
    }
    // ---- MLP head ----
    gemm_k<EPI_RELU><<<grid(B, 1024), blk, 0, stream>>>(
        decd, T * U, T * U, nullptr, 0, W_map, W_map, b_map,
        buf1, 1024, B, 1024, T * U);
    gemm_k<EPI_TANH><<<grid(B, 1024), blk, 0, stream>>>(
        buf1, 1024, 1024, nullptr, 0, W1, W1, b1, buf2, 1024, B, 1024, 1024);
    gemm_k<EPI_TANH><<<grid(B, 1024), blk, 0, stream>>>(
        buf2, 1024, 1024, nullptr, 0, W2, W2, b2, buf1, 1024, B, 1024, 1024);
    gemm_k<EPI_TANH><<<grid(B, 1024), blk, 0, stream>>>(
        buf1, 1024, 1024, nullptr, 0, W3, W3, b3, buf2, 1024, B, 1024, 1024);
    gemm_k<EPI_BIAS><<<grid(B, 168), blk, 0, stream>>>(
        buf2, 1024, 1024, nullptr, 0, W_out, W_out, b_out,
        out, 168, B, 168, 1024);
}

// Round 2
// 985.540 us; speedup vs baseline: 5.0317x; 5.0317x over previous
//
#include <hip/hip_runtime.h>
#include <math.h>

// ---------------------------------------------------------------------------
// Round 2: bf16 MFMA everywhere (fp32 accumulate), m97-style 128x128 tiles.
// A operands: bf16 [M][K] (K padded to %32). B operands: weights transposed
// per-launch into bf16 [Np][Kp], zero-padded (kills 0xAA poison in A pads).
// LSTM: Acat = [x_t | h] bf16; gates kernel (fp32) writes bf16 h in place.
// ---------------------------------------------------------------------------

using bf16x8 = __attribute__((ext_vector_type(8))) short;
using f32x4  = __attribute__((ext_vector_type(4))) float;

enum { EPI_NONE = 0, EPI_RELU = 1, EPI_TANH = 2 };

__device__ inline unsigned short f2bf(float f) {
    union { float f; unsigned u; } v; v.f = f;
    unsigned r = v.u + 0x7FFFu + ((v.u >> 16) & 1u);
    return (unsigned short)(r >> 16);
}

// async global->LDS, 16B per lane. LDS dest must be base + lane*16 (it is:
// chunk index == linear thread id within the staging loop).
__device__ inline void gll16(const void* g, void* l) {
    __builtin_amdgcn_global_load_lds(
        (const __attribute__((address_space(1))) unsigned int*)(uintptr_t)g,
        (__attribute__((address_space(3))) unsigned int*)(unsigned int)(uintptr_t)l,
        16, 0, 0);
}

// C[M,Np] = act(A[M,K] @ Bt[Np,K]^T + bias). M%128==0, Np%128==0, K%32==0.
// 256 thr = 4 waves in 2x2, each wave 64x64 via 4x4 of 16x16x32 MFMA.
template <int EPI, int OUT_BF16, int NGUARD>
__global__ __launch_bounds__(256)
void gemm_mfma(const unsigned short* __restrict__ A,
               const unsigned short* __restrict__ Bt,
               const float* __restrict__ bias,
               void* __restrict__ Cv, int ldc, int Nreal, int K)
{
    __shared__ __attribute__((aligned(16))) unsigned short As[128 * 32];
    __shared__ __attribute__((aligned(16))) unsigned short Bs[128 * 32];

    const int tid  = threadIdx.x;
    const int lane = tid & 63;
    const int w    = tid >> 6;
    const int wr   = w >> 1, wc = w & 1;
    const int lm   = lane & 15, quad = lane >> 4;
    const int m0   = blockIdx.x * 128, n0 = blockIdx.y * 128;

    f32x4 acc[4][4] = {};

    for (int k0 = 0; k0 < K; k0 += 32) {
        #pragma unroll
        for (int j = 0; j < 2; ++j) {
            const int idx = j * 256 + tid;           // 16B chunk id
            const int row = idx >> 2, kc = idx & 3;  // 4 chunks per 64B row
            gll16(A  + (size_t)(m0 + row) * K + k0 + kc * 8, As + idx * 8);
            gll16(Bt + (size_t)(n0 + row) * K + k0 + kc * 8, Bs + idx * 8);
        }
        __syncthreads();  // drains vmcnt (compiler emits waitcnt before barrier)

        bf16x8 aF[4], bF[4];
        #pragma unroll
        for (int mi = 0; mi < 4; ++mi)
            aF[mi] = *(const bf16x8*)(As + (wr * 64 + mi * 16 + lm) * 32 + quad * 8);
        #pragma unroll
        for (int ni = 0; ni < 4; ++ni)
            bF[ni] = *(const bf16x8*)(Bs + (wc * 64 + ni * 16 + lm) * 32 + quad * 8);
        #pragma unroll
        for (int mi = 0; mi < 4; ++mi)
            #pragma unroll
            for (int ni = 0; ni < 4; ++ni)
                acc[mi][ni] = __builtin_amdgcn_mfma_f32_16x16x32_bf16(
                    aF[mi], bF[ni], acc[mi][ni], 0, 0, 0);
        __syncthreads();
    }

    // C/D layout: col = lane&15, row = quad*4 + reg (verified m89/m91)
    #pragma unroll
    for (int mi = 0; mi < 4; ++mi)
        #pragma unroll
        for (int r = 0; r < 4; ++r) {
            const size_t row = m0 + wr * 64 + mi * 16 + quad * 4 + r;
            #pragma unroll
            for (int ni = 0; ni < 4; ++ni) {
                const int col = n0 + wc * 64 + ni * 16 + lm;
                if (!NGUARD || col < Nreal) {
                    float v = acc[mi][ni][r] + bias[col];
                    if (EPI == EPI_RELU) v = fmaxf(v, 0.f);
                    if (EPI == EPI_TANH) v = tanhf(v);
                    if (OUT_BF16) ((unsigned short*)Cv)[row * ldc + col] = f2bf(v);
                    else          ((float*)Cv)[row * ldc + col] = v;
                }
            }
        }
}

// [W1;W2] (fp32, [K][N] stacked at K1) -> Wt bf16 [Np][Kp], zero-padded.
__global__ void transpose_pack(const float* __restrict__ Wa,
                               const float* __restrict__ Wb, int K1,
                               int K, int N,
                               unsigned short* __restrict__ Wt, int Kp, int Np)
{
    __shared__ float t[32][33];
    const int n0 = blockIdx.x * 32, k0 = blockIdx.y * 32;
    const int tx = threadIdx.x, ty = threadIdx.y;
    #pragma unroll
    for (int r = 0; r < 4; ++r) {
        const int k = k0 + ty + 8 * r, n = n0 + tx;
        float v = 0.f;
        if (k < K && n < N)
            v = (k < K1) ? Wa[(size_t)k * N + n] : Wb[(size_t)(k - K1) * N + n];
        t[ty + 8 * r][tx] = v;
    }
    __syncthreads();
    #pragma unroll
    for (int r = 0; r < 4; ++r) {
        const int k = k0 + tx, n = n0 + ty + 8 * r;
        Wt[(size_t)n * Kp + k] = f2bf(t[tx][ty + 8 * r]);
    }
}

// convert one time-slice of x/m (fp32) into the bf16 concat buffer, col 0..F
__global__ void conv_slice(const float* __restrict__ src, int srow,
                           unsigned short* __restrict__ dst, int ldd,
                           int F, int n)
{
    const int i = blockIdx.x * 256 + threadIdx.x;
    if (i >= n) return;
    const int b = i / F, f = i - b * F;
    dst[(size_t)b * ldd + f] = f2bf(src[(size_t)b * srow + f]);
}

// gate math in fp32; writes bf16 h into the next GEMM's concat buffer
// (and optionally the decoded buffer).
__global__ void lstm_gates(const float* __restrict__ z, int ldz,
                           float* __restrict__ c,
                           unsigned short* __restrict__ hdst, int ldh, int hoff,
                           unsigned short* __restrict__ dec, int lddec, int doff,
                           int n, int Uc)
{
    const int i = blockIdx.x * 256 + threadIdx.x;
    if (i >= n) return;
    const int b = i / Uc, u = i - b * Uc;
    const float* zb = z + (size_t)b * ldz;
    const float zi = zb[u], zf = zb[u + Uc], zg = zb[u + 2 * Uc], zo = zb[u + 3 * Uc];
    const float ig = 1.f / (1.f + expf(-zi));
    const float fg = 1.f / (1.f + expf(-zf));
    const float og = 1.f / (1.f + expf(-zo));
    const float cv = fg * c[i] + ig * tanhf(zg);
    c[i] = cv;
    const unsigned short hb = f2bf(og * tanhf(cv));
    hdst[(size_t)b * ldh + hoff + u] = hb;
    if (dec) dec[(size_t)b * lddec + doff + u] = hb;
}

extern "C" void kernel_launch(void* const* d_in, const int* in_sizes, int n_in,
                              void* d_out, int out_size, void* d_ws, size_t ws_size,
                              hipStream_t stream)
{
    const float* x     = (const float*)d_in[0];
    const float* m     = (const float*)d_in[1];
    const float* enc_W = (const float*)d_in[2];
    const float* enc_U = (const float*)d_in[3];
    const float* enc_b = (const float*)d_in[4];
    const float* dec_W = (const float*)d_in[5];
    const float* dec_Um= (const float*)d_in[6];
    const float* dec_b = (const float*)d_in[7];
    const float* W_map = (const float*)d_in[8];
    const float* b_map = (const float*)d_in[9];
    const float* W1    = (const float*)d_in[10];
    const float* b1    = (const float*)d_in[11];
    const float* W2    = (const float*)d_in[12];
    const float* b2    = (const float*)d_in[13];
    const float* W3    = (const float*)d_in[14];
    const float* b3    = (const float*)d_in[15];
    const float* W_out = (const float*)d_in[16];
    const float* b_out = (const float*)d_in[17];
    float* out = (float*)d_out;

    const int B = 8192, T = 7, Uc = 356;
    const int FE = 69, FD = 45;
    const int KE = 448, KD = 416;         // pad32(69+356), pad32(45+356)
    const int NZ = 1424, NZP = 1536;      // 4U, pad128
    const int KM = 2492, KMP = 2496;      // 7U, pad32

    char* ws = (char*)d_ws;
    size_t off = 0;
    auto alloc = [&](size_t bytes) -> void* {
        void* p = ws + off; off = (off + bytes + 255) & ~(size_t)255; return p;
    };
    unsigned short* WtE = (unsigned short*)alloc((size_t)NZP * KE * 2);
    unsigned short* WtD = (unsigned short*)alloc((size_t)NZP * KD * 2);
    unsigned short* WtM = (unsigned short*)alloc((size_t)1024 * KMP * 2);
    unsigned short* Wt1 = (unsigned short*)alloc((size_t)1024 * 1024 * 2);
    unsigned short* Wt2 = (unsigned short*)alloc((size_t)1024 * 1024 * 2);
    unsigned short* Wt3 = (unsigned short*)alloc((size_t)1024 * 1024 * 2);
    unsigned short* WtO = (unsigned short*)alloc((size_t)256 * 1024 * 2);
    unsigned short* AcE = (unsigned short*)alloc((size_t)B * KE * 2);
    unsigned short* AcD = (unsigned short*)alloc((size_t)B * KD * 2);
    unsigned short* dcd = (unsigned short*)alloc((size_t)B * KMP * 2);
    unsigned short* a1  = (unsigned short*)alloc((size_t)B * 1024 * 2);
    unsigned short* a2  = (unsigned short*)alloc((size_t)B * 1024 * 2);
    float* z = (float*)alloc((size_t)B * NZ * 4);
    float* c = (float*)alloc((size_t)B * Uc * 4);

    const dim3 tb(32, 8);
    transpose_pack<<<dim3(NZP / 32, KE / 32), tb, 0, stream>>>(
        enc_W, enc_U, FE, FE + Uc, NZ, WtE, KE, NZP);
    transpose_pack<<<dim3(NZP / 32, KD / 32), tb, 0, stream>>>(
        dec_W, dec_Um, FD, FD + Uc, NZ, WtD, KD, NZP);
    transpose_pack<<<dim3(1024 / 32, KMP / 32), tb, 0, stream>>>(
        W_map, W_map, KM, KM, 1024, WtM, KMP, 1024);
    transpose_pack<<<dim3(32, 32), tb, 0, stream>>>(
        W1, W1, 1024, 1024, 1024, Wt1, 1024, 1024);
    transpose_pack<<<dim3(32, 32), tb, 0, stream>>>(
        W2, W2, 1024, 1024, 1024, Wt2, 1024, 1024);
    transpose_pack<<<dim3(32, 32), tb, 0, stream>>>(
        W3, W3, 1024, 1024, 1024, Wt3, 1024, 1024);
    transpose_pack<<<dim3(256 / 32, 1024 / 32), tb, 0, stream>>>(
        W_out, W_out, 1024, 1024, 168, WtO, 1024, 256);

    hipMemsetAsync(AcE, 0, (size_t)B * KE * 2, stream);  // h=0 + zero pads
    hipMemsetAsync(AcD, 0, (size_t)B * KD * 2, stream);
    hipMemsetAsync(c, 0, (size_t)B * Uc * 4, stream);

    const int nBU = B * Uc;
    const dim3 gz(64, NZP / 128);
    for (int t = 0; t < T; ++t) {
        conv_slice<<<(B * FE + 255) / 256, 256, 0, stream>>>(
            x + t * FE, T * FE, AcE, KE, FE, B * FE);
        gemm_mfma<EPI_NONE, 0, 1><<<gz, 256, 0, stream>>>(
            AcE, WtE, enc_b, z, NZ, NZ, KE);
        const bool last = (t == T - 1);
        lstm_gates<<<(nBU + 255) / 256, 256, 0, stream>>>(
            z, NZ, c, last ? AcD : AcE, last ? KD : KE, last ? FD : FE,
            nullptr, 0, 0, nBU, Uc);
    }
    for (int t = 0; t < T; ++t) {
        conv_slice<<<(B * FD + 255) / 256, 256, 0, stream>>>(
            m + t * FD, T * FD, AcD, KD, FD, B * FD);
        gemm_mfma<EPI_NONE, 0, 1><<<gz, 256, 0, stream>>>(
            AcD, WtD, dec_b, z, NZ, NZ, KD);
        lstm_gates<<<(nBU + 255) / 256, 256, 0, stream>>>(
            z, NZ, c, AcD, KD, FD, dcd, KMP, t * Uc, nBU, Uc);
    }
    gemm_mfma<EPI_RELU, 1, 0><<<dim3(64, 8), 256, 0, stream>>>(
        dcd, WtM, b_map, a1, 1024, 1024, KMP);
    gemm_mfma<EPI_TANH, 1, 0><<<dim3(64, 8), 256, 0, stream>>>(
        a1, Wt1, b1, a2, 1024, 1024, 1024);
    gemm_mfma<EPI_TANH, 1, 0><<<dim3(64, 8), 256, 0, stream>>>(
        a2, Wt2, b2, a1, 1024, 1024, 1024);
    gemm_mfma<EPI_TANH, 1, 0><<<dim3(64, 8), 256, 0, stream>>>(
        a1, Wt3, b3, a2, 1024, 1024, 1024);
    gemm_mfma<EPI_NONE, 0, 1><<<dim3(64, 2), 256, 0, stream>>>(
        a2, WtO, b_out, out, 168, 168, 1024);
}

// Round 3
// 759.322 us; speedup vs baseline: 6.5307x; 1.2979x over previous
//
#include <hip/hip_runtime.h>
#include <math.h>

// ---------------------------------------------------------------------------
// Round 3: LSTM gates fused into GEMM epilogue via gate-interleaved weight
// layout  n' = (u>>4)*64 + gate*16 + (u&15)  -> each wave's 64-col tile holds
// all 4 gates for 16 units; each lane's 4 ni-accumulators are (i,f,g,o) of
// one unit. Per-timestep concat A buffers pre-filled; sequential chain is
// 14 bare GEMM launches. MLP unchanged from round 2.
// ---------------------------------------------------------------------------

using bf16x8 = __attribute__((ext_vector_type(8))) short;
using f32x4  = __attribute__((ext_vector_type(4))) float;

enum { EPI_NONE = 0, EPI_RELU = 1, EPI_TANH = 2 };

__device__ inline unsigned short f2bf(float f) {
    union { float f; unsigned u; } v; v.f = f;
    unsigned r = v.u + 0x7FFFu + ((v.u >> 16) & 1u);
    return (unsigned short)(r >> 16);
}
__device__ inline float sigf(float x) { return 1.f / (1.f + expf(-x)); }

__device__ inline void gll16(const void* g, void* l) {
    __builtin_amdgcn_global_load_lds(
        (const __attribute__((address_space(1))) unsigned int*)(uintptr_t)g,
        (__attribute__((address_space(3))) unsigned int*)(unsigned int)(uintptr_t)l,
        16, 0, 0);
}

// ---- shared GEMM core macro-body: stages 128x32 A/B tiles, 4 waves 2x2 ----
#define GEMM_CORE(A_, Bt_, K_)                                                 \
    __shared__ __attribute__((aligned(16))) unsigned short As[128 * 32];       \
    __shared__ __attribute__((aligned(16))) unsigned short Bs[128 * 32];       \
    const int tid  = threadIdx.x;                                              \
    const int lane = tid & 63;                                                 \
    const int w    = tid >> 6;                                                 \
    const int wr   = w >> 1, wc = w & 1;                                       \
    const int lm   = lane & 15, quad = lane >> 4;                              \
    const int m0   = blockIdx.x * 128, n0 = blockIdx.y * 128;                  \
    f32x4 acc[4][4] = {};                                                      \
    for (int k0 = 0; k0 < (K_); k0 += 32) {                                    \
        _Pragma("unroll")                                                      \
        for (int j = 0; j < 2; ++j) {                                          \
            const int idx = j * 256 + tid;                                     \
            const int row = idx >> 2, kc = idx & 3;                            \
            gll16((A_)  + (size_t)(m0 + row) * (K_) + k0 + kc * 8, As + idx*8);\
            gll16((Bt_) + (size_t)(n0 + row) * (K_) + k0 + kc * 8, Bs + idx*8);\
        }                                                                      \
        __syncthreads();                                                       \
        bf16x8 aF[4], bF[4];                                                   \
        _Pragma("unroll")                                                      \
        for (int mi = 0; mi < 4; ++mi)                                         \
            aF[mi] = *(const bf16x8*)(As + (wr*64 + mi*16 + lm)*32 + quad*8);  \
        _Pragma("unroll")                                                      \
        for (int ni = 0; ni < 4; ++ni)                                         \
            bF[ni] = *(const bf16x8*)(Bs + (wc*64 + ni*16 + lm)*32 + quad*8);  \
        _Pragma("unroll")                                                      \
        for (int mi = 0; mi < 4; ++mi)                                         \
            _Pragma("unroll")                                                  \
            for (int ni = 0; ni < 4; ++ni)                                     \
                acc[mi][ni] = __builtin_amdgcn_mfma_f32_16x16x32_bf16(         \
                    aF[mi], bF[ni], acc[mi][ni], 0, 0, 0);                     \
        __syncthreads();                                                       \
    }

// ---- plain GEMM (MLP): C = act(A @ Bt^T + bias) ----
template <int EPI, int OUT_BF16, int NGUARD>
__global__ __launch_bounds__(256)
void gemm_mfma(const unsigned short* __restrict__ A,
               const unsigned short* __restrict__ Bt,
               const float* __restrict__ bias,
               void* __restrict__ Cv, int ldc, int Nreal, int K)
{
    GEMM_CORE(A, Bt, K)
    #pragma unroll
    for (int mi = 0; mi < 4; ++mi)
        #pragma unroll
        for (int r = 0; r < 4; ++r) {
            const size_t row = m0 + wr * 64 + mi * 16 + quad * 4 + r;
            #pragma unroll
            for (int ni = 0; ni < 4; ++ni) {
                const int col = n0 + wc * 64 + ni * 16 + lm;
                if (!NGUARD || col < Nreal) {
                    float v = acc[mi][ni][r] + bias[col];
                    if (EPI == EPI_RELU) v = fmaxf(v, 0.f);
                    if (EPI == EPI_TANH) v = tanhf(v);
                    if (OUT_BF16) ((unsigned short*)Cv)[row * ldc + col] = f2bf(v);
                    else          ((float*)Cv)[row * ldc + col] = v;
                }
            }
        }
}

// ---- LSTM GEMM: z = A @ Wt^T + biasI, then gates fused in epilogue. ----
// Wt columns interleaved: n' = (u>>4)*64 + g*16 + (u&15). Each lane's 4 ni
// accs = gates (i,f,g,o) of unit u = ((n0+wc*64)>>6)*16 + lm.
__global__ __launch_bounds__(256)
void gemm_lstm(const unsigned short* __restrict__ A,
               const unsigned short* __restrict__ Bt,
               const float* __restrict__ biasI,
               float* __restrict__ c,
               unsigned short* __restrict__ hdst, int ldh, int hoff,
               unsigned short* __restrict__ dec, int doff, int K)
{
    GEMM_CORE(A, Bt, K)
    const int u = ((n0 + wc * 64) >> 6) * 16 + lm;
    if (u >= 356) return;
    float bI[4];
    #pragma unroll
    for (int ni = 0; ni < 4; ++ni) bI[ni] = biasI[n0 + wc * 64 + ni * 16 + lm];
    #pragma unroll
    for (int mi = 0; mi < 4; ++mi)
        #pragma unroll
        for (int r = 0; r < 4; ++r) {
            const size_t row = m0 + wr * 64 + mi * 16 + quad * 4 + r;
            const float zi = acc[mi][0][r] + bI[0];
            const float zf = acc[mi][1][r] + bI[1];
            const float zg = acc[mi][2][r] + bI[2];
            const float zo = acc[mi][3][r] + bI[3];
            const size_t ci = row * 356 + u;
            const float cn = sigf(zf) * c[ci] + sigf(zi) * tanhf(zg);
            c[ci] = cn;
            const unsigned short hb = f2bf(sigf(zo) * tanhf(cn));
            if (hdst) hdst[row * (size_t)ldh + hoff + u] = hb;
            if (dec)  dec[row * (size_t)2496 + doff + u] = hb;
        }
}

// ---- LSTM weight pack: [Wa;Wb] fp32 [K][1424] -> Wt bf16 [1536][Kp],
// col-interleaved, zero-padded; also biasI. ----
__global__ void pack_lstm(const float* __restrict__ Wa,
                          const float* __restrict__ Wb, int K1, int K,
                          const float* __restrict__ bias,
                          unsigned short* __restrict__ Wt,
                          float* __restrict__ biasI, int Kp)
{
    const int idx = blockIdx.x * 256 + threadIdx.x;
    if (idx >= 1536 * Kp) return;
    const int np = idx / Kp, k = idx - np * Kp;
    const int ub = np >> 6, g = (np >> 4) & 3, ul = np & 15;
    const int u = ub * 16 + ul;
    const bool valid = (u < 356);
    const int norig = g * 356 + u;
    float v = 0.f;
    if (valid && k < K)
        v = (k < K1) ? Wa[(size_t)k * 1424 + norig]
                     : Wb[(size_t)(k - K1) * 1424 + norig];
    Wt[(size_t)np * Kp + k] = f2bf(v);
    if (k == 0) biasI[np] = valid ? bias[norig] : 0.f;
}

// ---- MLP weight transpose+pack (fp32 [K][N] -> bf16 [Np][Kp], zero-pad) ----
__global__ void transpose_pack(const float* __restrict__ W, int K, int N,
                               unsigned short* __restrict__ Wt, int Kp, int Np)
{
    __shared__ float t[32][33];
    const int n0 = blockIdx.x * 32, k0 = blockIdx.y * 32;
    const int tx = threadIdx.x, ty = threadIdx.y;
    #pragma unroll
    for (int r = 0; r < 4; ++r) {
        const int k = k0 + ty + 8 * r, n = n0 + tx;
        t[ty + 8 * r][tx] = (k < K && n < N) ? W[(size_t)k * N + n] : 0.f;
    }
    __syncthreads();
    #pragma unroll
    for (int r = 0; r < 4; ++r) {
        const int k = k0 + tx, n = n0 + ty + 8 * r;
        if (k < Kp && n < Np) Wt[(size_t)n * Kp + k] = f2bf(t[tx][ty + 8 * r]);
    }
}

// ---- fill x/m time-slices into the 7 per-step concat buffers (bf16) ----
__global__ void fill_slices(const float* __restrict__ src,
                            unsigned short* __restrict__ bufs,
                            int F, int Kp, int n)  // n = B*7*F
{
    const int i = blockIdx.x * 256 + threadIdx.x;
    if (i >= n) return;
    const int b = i / (7 * F), rem = i - b * 7 * F;
    const int t = rem / F, f = rem - t * F;
    bufs[(size_t)t * 8192 * Kp + (size_t)b * Kp + f] = f2bf(src[i]);
}

extern "C" void kernel_launch(void* const* d_in, const int* in_sizes, int n_in,
                              void* d_out, int out_size, void* d_ws, size_t ws_size,
                              hipStream_t stream)
{
    const float* x     = (const float*)d_in[0];
    const float* m     = (const float*)d_in[1];
    const float* enc_W = (const float*)d_in[2];
    const float* enc_U = (const float*)d_in[3];
    const float* enc_b = (const float*)d_in[4];
    const float* dec_W = (const float*)d_in[5];
    const float* dec_Um= (const float*)d_in[6];
    const float* dec_b = (const float*)d_in[7];
    const float* W_map = (const float*)d_in[8];
    const float* b_map = (const float*)d_in[9];
    const float* W1    = (const float*)d_in[10];
    const float* b1    = (const float*)d_in[11];
    const float* W2    = (const float*)d_in[12];
    const float* b2    = (const float*)d_in[13];
    const float* W3    = (const float*)d_in[14];
    const float* b3    = (const float*)d_in[15];
    const float* W_out = (const float*)d_in[16];
    const float* b_out = (const float*)d_in[17];
    float* out = (float*)d_out;

    const int B = 8192, T = 7, FE = 69, FD = 45;
    const int KE = 448, KD = 416;     // pad32(69+356), pad32(45+356)
    const int KMP = 2496;             // pad32(7*356)

    char* ws = (char*)d_ws;
    size_t off = 0;
    auto alloc = [&](size_t bytes) -> void* {
        void* p = ws + off; off = (off + bytes + 255) & ~(size_t)255; return p;
    };
    unsigned short* WtE = (unsigned short*)alloc((size_t)1536 * KE * 2);
    unsigned short* WtD = (unsigned short*)alloc((size_t)1536 * KD * 2);
    unsigned short* WtM = (unsigned short*)alloc((size_t)1024 * KMP * 2);
    unsigned short* Wt1 = (unsigned short*)alloc((size_t)1024 * 1024 * 2);
    unsigned short* Wt2 = (unsigned short*)alloc((size_t)1024 * 1024 * 2);
    unsigned short* Wt3 = (unsigned short*)alloc((size_t)1024 * 1024 * 2);
    unsigned short* WtO = (unsigned short*)alloc((size_t)256 * 1024 * 2);
    float* bIE = (float*)alloc(1536 * 4);
    float* bID = (float*)alloc(1536 * 4);
    unsigned short* AcE = (unsigned short*)alloc((size_t)T * B * KE * 2);
    unsigned short* AcD = (unsigned short*)alloc((size_t)T * B * KD * 2);
    unsigned short* dcd = (unsigned short*)alloc((size_t)B * KMP * 2);
    unsigned short* a1  = (unsigned short*)alloc((size_t)B * 1024 * 2);
    unsigned short* a2  = (unsigned short*)alloc((size_t)B * 1024 * 2);
    float* c = (float*)alloc((size_t)B * 356 * 4);

    // ---- weight packing (parallel, off critical path) ----
    pack_lstm<<<(1536 * KE + 255) / 256, 256, 0, stream>>>(
        enc_W, enc_U, FE, FE + 356, enc_b, WtE, bIE, KE);
    pack_lstm<<<(1536 * KD + 255) / 256, 256, 0, stream>>>(
        dec_W, dec_Um, FD, FD + 356, dec_b, WtD, bID, KD);
    const dim3 tb(32, 8);
    transpose_pack<<<dim3(1024 / 32, KMP / 32), tb, 0, stream>>>(
        W_map, 2492, 1024, WtM, KMP, 1024);
    transpose_pack<<<dim3(32, 32), tb, 0, stream>>>(W1, 1024, 1024, Wt1, 1024, 1024);
    transpose_pack<<<dim3(32, 32), tb, 0, stream>>>(W2, 1024, 1024, Wt2, 1024, 1024);
    transpose_pack<<<dim3(32, 32), tb, 0, stream>>>(W3, 1024, 1024, Wt3, 1024, 1024);
    transpose_pack<<<dim3(256 / 32, 1024 / 32), tb, 0, stream>>>(
        W_out, 1024, 168, WtO, 1024, 256);

    // ---- zero state + A buffers (pads must be 0; ws is 0xAA-poisoned) ----
    hipMemsetAsync(AcE, 0, (size_t)T * B * KE * 2, stream);
    hipMemsetAsync(AcD, 0, (size_t)T * B * KD * 2, stream);
    hipMemsetAsync(dcd, 0, (size_t)B * KMP * 2, stream);
    hipMemsetAsync(c,   0, (size_t)B * 356 * 4, stream);

    fill_slices<<<(B * T * FE + 255) / 256, 256, 0, stream>>>(x, AcE, FE, KE, B * T * FE);
    fill_slices<<<(B * T * FD + 255) / 256, 256, 0, stream>>>(m, AcD, FD, KD, B * T * FD);

    // ---- sequential LSTM chain: 14 fused GEMM launches ----
    const dim3 gz(64, 12);
    for (int t = 0; t < T; ++t) {
        unsigned short* At = AcE + (size_t)t * B * KE;
        unsigned short* hdst = (t < 6) ? AcE + (size_t)(t + 1) * B * KE : AcD;
        gemm_lstm<<<gz, 256, 0, stream>>>(
            At, WtE, bIE, c, hdst, (t < 6) ? KE : KD, (t < 6) ? FE : FD,
            nullptr, 0, KE);
    }
    for (int t = 0; t < T; ++t) {
        unsigned short* At = AcD + (size_t)t * B * KD;
        unsigned short* hdst = (t < 6) ? AcD + (size_t)(t + 1) * B * KD : nullptr;
        gemm_lstm<<<gz, 256, 0, stream>>>(
            At, WtD, bID, c, hdst, KD, FD, dcd, t * 356, KD);
    }

    // ---- MLP head ----
    gemm_mfma<EPI_RELU, 1, 0><<<dim3(64, 8), 256, 0, stream>>>(
        dcd, WtM, b_map, a1, 1024, 1024, KMP);
    gemm_mfma<EPI_TANH, 1, 0><<<dim3(64, 8), 256, 0, stream>>>(
        a1, Wt1, b1, a2, 1024, 1024, 1024);
    gemm_mfma<EPI_TANH, 1, 0><<<dim3(64, 8), 256, 0, stream>>>(
        a2, Wt2, b2, a1, 1024, 1024, 1024);
    gemm_mfma<EPI_TANH, 1, 0><<<dim3(64, 8), 256, 0, stream>>>(
        a1, Wt3, b3, a2, 1024, 1024, 1024);
    gemm_mfma<EPI_NONE, 0, 1><<<dim3(64, 2), 256, 0, stream>>>(
        a2, WtO, b_out, out, 168, 168, 1024);
}